// Round 5
// baseline (233.291 us; speedup 1.0000x reference)
//
#include <hip/hip_runtime.h>

// ---------------- problem constants ----------------
#define NB        8
#define NPB       120000
#define NPTS      (NB * NPB)       // 960000
#define MAX_PTS   10
#define MAX_VOX   40000
#define GX        704
#define GY        800
#define GZ        20

#define HC        (1 << 18)        // hash capacity per batch (load ~0.4)
#define HMASK     (HC - 1)
#define NSLOT     (NB * HC)        // 2M slots
#define TILES     469              // ceil(120000 / 256)
#define TILES_PAD 512
#define MBCAP     8192             // per-batch multi list capacity (~500 expected)
#define MTILE     2048             // LDS staging tile for k_multi

#define EMPTY64   0xFFFFFFFFFFFFFFFFull

// output layout (flat float32)
#define OUT_VOX   0LL
#define OUT_NUM   12800000LL
#define OUT_COOR  13120000LL
#define OUT_GRID  14400000LL

// hash: slab[s] = (lid<<32)|minidx (8B: CAS claim / atomicMin)
//       ext[s]  = count-1 (atomicAdd by non-claimers only, ~4k ops total)
__device__ __forceinline__ bool point_cell(const float* __restrict__ p,
                                           int& cx, int& cy, int& cz) {
    // must match numpy f32: floor((xyz - PC_MIN) / VSIZE)
    cx = (int)floorf((p[1] - 0.0f)   / 0.1f);
    cy = (int)floorf((p[2] - (-40.0f)) / 0.1f);
    cz = (int)floorf((p[3] - (-3.0f))  / 0.2f);
    return (cx >= 0) & (cx < GX) & (cy >= 0) & (cy < GY) & (cz >= 0) & (cz < GZ);
}

// ---------------- K0: init hash + flagcnt + coors/num ----------------
__global__ void k_init(float* __restrict__ out, ulonglong2* __restrict__ slab2,
                       uint4* __restrict__ ext4, uint4* __restrict__ fc4,
                       unsigned* __restrict__ mcount) {
    int t = blockIdx.x * blockDim.x + threadIdx.x;
    int stride = gridDim.x * blockDim.x;
    ulonglong2 e2; e2.x = EMPTY64; e2.y = EMPTY64;
    for (int i = t; i < NSLOT / 2; i += stride) slab2[i] = e2;          // 16 MB
    uint4 z4 = make_uint4(0u, 0u, 0u, 0u);
    for (int i = t; i < NSLOT / 4; i += stride) ext4[i] = z4;           // 8 MB
    for (int i = t; i < NPTS / 4; i += stride) fc4[i] = z4;             // 3.84 MB
    for (int i = t; i < NB * MAX_VOX / 4; i += stride)
        ((float4*)(out + OUT_NUM))[i] = make_float4(0.f, 0.f, 0.f, 0.f);
    float4* c4 = (float4*)(out + OUT_COOR);
    for (int i = t; i < NB * MAX_VOX; i += stride) {
        int b = i / MAX_VOX;
        c4[i] = make_float4((float)b, -1.f, -1.f, -1.f);
    }
    if (t < NB) mcount[t] = 0u;
    if (t == 0) {
        out[OUT_GRID + 0] = 704.f;
        out[OUT_GRID + 1] = 800.f;
        out[OUT_GRID + 2] = 20.f;
    }
}

// ---------------- K1: per-point hash insert (read-first probe, claimer skips count) ----------------
__global__ void k_phase1(const float* __restrict__ pts,
                         unsigned long long* __restrict__ slab,
                         unsigned* __restrict__ ext,
                         int* __restrict__ pHash) {
    int g = blockIdx.x * blockDim.x + threadIdx.x;
    if (g >= NPTS) return;
    int b = g / NPB;
    int idx = g - b * NPB;
    const float* p = pts + (long long)g * 5;
    int cx, cy, cz;
    int slot = -1;
    if (point_cell(p, cx, cy, cz)) {
        int lid = (cz * GY + cy) * GX + cx;
        unsigned h = (((unsigned)lid * 2654435761u) >> 14) & HMASK;
        unsigned long long key = ((unsigned long long)(unsigned)lid << 32)
                               | (unsigned long long)(unsigned)idx;
        int base = b * HC;
        while (true) {
            unsigned long long* wp = &slab[base + (int)h];
            unsigned long long cur = *((volatile unsigned long long*)wp);  // cheap probe
            if (cur == EMPTY64) {
                unsigned long long old = atomicCAS(wp, EMPTY64, key);
                if (old == EMPTY64) { slot = base + (int)h; break; }       // claimed
                cur = old;                                                 // lost race
            }
            if ((unsigned)(cur >> 32) == (unsigned)lid) {                  // same cell (rare path)
                slot = base + (int)h;
                atomicMin(wp, key);                                        // stale-safe
                atomicAdd(&ext[slot], 1u);                                 // extra = count-1
                break;
            }
            h = (h + 1) & HMASK;
        }
    }
    pHash[g] = slot;
}

// ---------------- K2: slots -> per-point leader count array (streaming slab read) ----------------
__global__ void k_slots(const unsigned long long* __restrict__ slab,
                        const unsigned* __restrict__ ext,
                        unsigned* __restrict__ flagcnt) {
    int s = blockIdx.x * blockDim.x + threadIdx.x;
    if (s >= NSLOT) return;
    unsigned long long k = slab[s];
    if (k == EMPTY64) return;
    int b = s >> 18;                                // / HC
    unsigned minidx = (unsigned)k;
    flagcnt[b * NPB + (int)minidx] = ext[s] + 1u;   // unique writer per cell
}

// ---------------- K3: leader flag + per-tile scan (sequential flagcnt read) ----------------
__global__ void k_leader_scan(const unsigned* __restrict__ flagcnt,
                              int* __restrict__ rankT, int* __restrict__ tileSum) {
    int b = blockIdx.y;
    int tile = blockIdx.x;
    int idx = tile * 256 + threadIdx.x;
    int f = 0;
    if (idx < NPB) f = (flagcnt[b * NPB + idx] > 0u) ? 1 : 0;
    __shared__ int sc[256];
    sc[threadIdx.x] = f;
    __syncthreads();
    for (int off = 1; off < 256; off <<= 1) {
        int v = sc[threadIdx.x];
        if ((int)threadIdx.x >= off) v += sc[threadIdx.x - off];
        __syncthreads();
        sc[threadIdx.x] = v;
        __syncthreads();
    }
    if (idx < NPB) rankT[b * NPB + idx] = sc[threadIdx.x] - f;  // exclusive in tile
    if (threadIdx.x == 255) tileSum[b * TILES_PAD + tile] = sc[255];
}

// ---------------- K4: per-batch scan of tile sums ----------------
__global__ void k_scan_tiles(const int* __restrict__ tileSum, int* __restrict__ tileOff) {
    int b = blockIdx.x;
    int t = threadIdx.x;
    __shared__ int sc[512];
    int v = (t < TILES) ? tileSum[b * TILES_PAD + t] : 0;
    sc[t] = v;
    __syncthreads();
    for (int off = 1; off < 512; off <<= 1) {
        int x = sc[t];
        if (t >= off) x += sc[t - off];
        __syncthreads();
        sc[t] = x;
        __syncthreads();
    }
    if (t < TILES) tileOff[b * TILES_PAD + t] = sc[t] - v;      // exclusive
}

// ---------------- K5: leaders write full row + coors + num; non-leaders -> mlist ----------------
__global__ void k_finish(const float* __restrict__ pts, const int* __restrict__ pHash,
                         const unsigned long long* __restrict__ slab,
                         const unsigned* __restrict__ flagcnt,
                         const int* __restrict__ rankT, const int* __restrict__ tileOff,
                         float* __restrict__ out, int2* __restrict__ mlist,
                         unsigned* __restrict__ mcount) {
    int g = blockIdx.x * blockDim.x + threadIdx.x;
    if (g >= NPTS) return;
    int b = g / NPB;
    int idx = g - b * NPB;
    int hs = pHash[g];
    if (hs < 0) return;
    unsigned fc = flagcnt[g];
    if (fc > 0u) {                                               // leader: minidx == idx
        int slot = tileOff[b * TILES_PAD + (idx >> 8)] + rankT[g];
        if (slot >= MAX_VOX) return;
        long long r = (long long)b * MAX_VOX + slot;
        const float* p = pts + (long long)g * 5;                 // sequential read
        int cx, cy, cz;
        point_cell(p, cx, cy, cz);
        float4* cr = (float4*)(out + OUT_COOR + r * 4);
        *cr = make_float4((float)b, (float)cz, (float)cy, (float)cx);
        out[OUT_NUM + r] = (float)(fc < (unsigned)MAX_PTS ? fc : (unsigned)MAX_PTS);
        float4* row = (float4*)(out + OUT_VOX + r * (MAX_PTS * 4));
        row[0] = make_float4(p[1], p[2], p[3], p[4]);
        float4 z4 = make_float4(0.f, 0.f, 0.f, 0.f);
        #pragma unroll
        for (int i = 1; i < MAX_PTS; i++) row[i] = z4;           // zero rest of row
    } else {
        // non-leader => cell has >=2 points; rare (~500/batch): gather minidx
        unsigned minidx = (unsigned)slab[hs];
        unsigned m = atomicAdd(&mcount[b], 1u);
        if (m < MBCAP) mlist[(size_t)b * MBCAP + m] = make_int2((int)minidx, idx);
    }
}

// ---------------- K6: rank + scatter multi-cell non-leaders (LDS-staged, per batch) ----------------
__global__ void k_multi(const float* __restrict__ pts,
                        const int* __restrict__ rankT, const int* __restrict__ tileOff,
                        const int2* __restrict__ mlist, const unsigned* __restrict__ mcount,
                        float* __restrict__ out) {
    int b = blockIdx.y;
    unsigned n = mcount[b];
    if (n > MBCAP) n = MBCAP;
    unsigned t = blockIdx.x * blockDim.x + threadIdx.x;
    const int2* lst = mlist + (size_t)b * MBCAP;
    bool active = (t < n);
    int2 e = active ? lst[t] : make_int2(-1, -1);   // (minidx, idx)
    int pos = 1;                                    // leader (not in list) is pos 0
    __shared__ int2 sm[MTILE];
    for (unsigned chunk = 0; chunk < n; chunk += MTILE) {
        unsigned m = n - chunk;
        if (m > MTILE) m = MTILE;
        for (unsigned i = threadIdx.x; i < m; i += 256)
            sm[i] = lst[chunk + i];
        __syncthreads();
        if (active) {
            #pragma unroll 4
            for (unsigned j = 0; j < m; j++) {
                int2 o = sm[j];
                pos += (o.x == e.x && o.y < e.y);
            }
        }
        __syncthreads();
    }
    if (!active || pos >= MAX_PTS) return;
    int slot = tileOff[b * TILES_PAD + (e.x >> 8)] + rankT[b * NPB + e.x];
    if (slot >= MAX_VOX) return;
    const float* p = pts + ((long long)b * NPB + e.y) * 5;
    long long base = OUT_VOX + (((long long)b * MAX_VOX + slot) * MAX_PTS + pos) * 4;
    float4* dst = (float4*)(out + base);
    *dst = make_float4(p[1], p[2], p[3], p[4]);
}

extern "C" void kernel_launch(void* const* d_in, const int* in_sizes, int n_in,
                              void* d_out, int out_size, void* d_ws, size_t ws_size,
                              hipStream_t stream) {
    const float* pts = (const float*)d_in[0];
    float* out = (float*)d_out;

    char* w = (char*)d_ws;
    unsigned long long* slab = (unsigned long long*)w;
    w += (size_t)NSLOT * 8;                                      // 16 MB
    unsigned* ext = (unsigned*)w;   w += (size_t)NSLOT * 4;      // 8 MB
    unsigned* flagcnt = (unsigned*)w; w += (size_t)NPTS * 4;     // 3.84 MB
    int* pHash = (int*)w;    w += (size_t)NPTS * 4;              // 3.84 MB
    int* rankT = (int*)w;    w += (size_t)NPTS * 4;              // 3.84 MB
    int* tileSum = (int*)w;  w += (size_t)NB * TILES_PAD * 4;
    int* tileOff = (int*)w;  w += (size_t)NB * TILES_PAD * 4;
    int2* mlist = (int2*)w;  w += (size_t)NB * MBCAP * 8;        // 0.5 MB
    unsigned* mcount = (unsigned*)w; w += 256;

    k_init<<<dim3(4096), dim3(256), 0, stream>>>(out, (ulonglong2*)slab,
                                                 (uint4*)ext, (uint4*)flagcnt, mcount);
    k_phase1<<<dim3((NPTS + 255) / 256), dim3(256), 0, stream>>>(pts, slab, ext, pHash);
    k_slots<<<dim3(NSLOT / 256), dim3(256), 0, stream>>>(slab, ext, flagcnt);
    k_leader_scan<<<dim3(TILES, NB), dim3(256), 0, stream>>>(flagcnt, rankT, tileSum);
    k_scan_tiles<<<dim3(NB), dim3(512), 0, stream>>>(tileSum, tileOff);
    k_finish<<<dim3((NPTS + 255) / 256), dim3(256), 0, stream>>>(pts, pHash, slab, flagcnt,
                                                                 rankT, tileOff, out, mlist, mcount);
    k_multi<<<dim3(MBCAP / 256, NB), dim3(256), 0, stream>>>(pts, rankT, tileOff, mlist, mcount, out);
}

// Round 6
// 179.067 us; speedup vs baseline: 1.3028x; 1.3028x over previous
//
#include <hip/hip_runtime.h>

// ---------------- problem constants ----------------
#define NB        8
#define NPB       120000
#define NPTS      (NB * NPB)       // 960000
#define MAX_PTS   10
#define MAX_VOX   40000
#define GX        704
#define GY        800
#define GZ        20
#define CELLS     (GX * GY * GZ)   // 11,264,000 cells per batch
#define WPB       (CELLS / 32)     // 352,000 bitmap words per batch

#define HC2       (1 << 15)        // secondary hash slots per batch (colliders only)
#define HMASK2    (HC2 - 1)
#define NSLOT2    (NB * HC2)       // 262,144
#define TILES     469              // ceil(120000 / 256)
#define TILES_PAD 512
#define MBCAP     8192             // per-batch multi list capacity (~500 expected)
#define MTILE     2048

#define EMPTY64   0xFFFFFFFFFFFFFFFFull

// output layout (flat float32)
#define OUT_VOX   0LL
#define OUT_NUM   12800000LL
#define OUT_COOR  13120000LL
#define OUT_GRID  14400000LL

__device__ __forceinline__ bool point_cell(const float* __restrict__ p,
                                           int& cx, int& cy, int& cz) {
    // must match numpy f32: floor((xyz - PC_MIN) / VSIZE)
    cx = (int)floorf((p[1] - 0.0f)   / 0.1f);
    cy = (int)floorf((p[2] - (-40.0f)) / 0.1f);
    cz = (int)floorf((p[3] - (-3.0f))  / 0.2f);
    return (cx >= 0) & (cx < GX) & (cy >= 0) & (cy < GY) & (cz >= 0) & (cz < GZ);
}

// ---------------- K0: init bitmap + secondary hash + flags + coors/num ----------------
__global__ void k_init(float* __restrict__ out, uint4* __restrict__ bm4,
                       ulonglong2* __restrict__ slab2, uint4* __restrict__ flag4,
                       unsigned* __restrict__ mcount) {
    int t = blockIdx.x * blockDim.x + threadIdx.x;
    int stride = gridDim.x * blockDim.x;
    uint4 z4 = make_uint4(0u, 0u, 0u, 0u);
    for (int i = t; i < NB * WPB / 4; i += stride) bm4[i] = z4;          // 11.26 MB
    ulonglong2 e2; e2.x = EMPTY64; e2.y = EMPTY64;
    for (int i = t; i < NSLOT2 / 2; i += stride) slab2[i] = e2;          // 2 MB
    for (int i = t; i < NPTS / 16; i += stride) flag4[i] = z4;           // 0.96 MB (u8 flags)
    for (int i = t; i < NB * MAX_VOX / 4; i += stride)
        ((float4*)(out + OUT_NUM))[i] = make_float4(0.f, 0.f, 0.f, 0.f);
    float4* c4 = (float4*)(out + OUT_COOR);
    for (int i = t; i < NB * MAX_VOX; i += stride) {
        int b = i / MAX_VOX;
        c4[i] = make_float4((float)b, -1.f, -1.f, -1.f);
    }
    if (t < NB) mcount[t] = 0u;
    if (t == 0) {
        out[OUT_GRID + 0] = 704.f;
        out[OUT_GRID + 1] = 800.f;
        out[OUT_GRID + 2] = 20.f;
    }
}

// ---------------- K1: bitmap claim; colliders -> secondary hash ----------------
__global__ void k_phase1(const float* __restrict__ pts, unsigned* __restrict__ bm,
                         unsigned long long* __restrict__ slabB,
                         unsigned char* __restrict__ flag) {
    int g = blockIdx.x * blockDim.x + threadIdx.x;
    if (g >= NPTS) return;
    int b = g / NPB;
    int idx = g - b * NPB;
    const float* p = pts + (long long)g * 5;
    int cx, cy, cz;
    if (!point_cell(p, cx, cy, cz)) return;
    int lid = (cz * GY + cy) * GX + cx;
    unsigned mask = 1u << (lid & 31);
    unsigned old = atomicOr(&bm[b * WPB + (lid >> 5)], mask);
    if ((old & mask) == 0u) {
        flag[g] = 1;                                   // claimer (provisional leader)
    } else {
        // collider (rare ~4k total): register in secondary hash w/ min idx
        unsigned h = (((unsigned)lid * 2654435761u) >> 17) & HMASK2;
        unsigned long long key = ((unsigned long long)(unsigned)lid << 32)
                               | (unsigned long long)(unsigned)idx;
        int base2 = b * HC2;
        while (true) {
            unsigned long long* wp = &slabB[base2 + (int)h];
            unsigned long long cur = *((volatile unsigned long long*)wp);
            if (cur == EMPTY64) {
                unsigned long long o = atomicCAS(wp, EMPTY64, key);
                if (o == EMPTY64) break;
                cur = o;
            }
            if ((unsigned)(cur >> 32) == (unsigned)lid) { atomicMin(wp, key); break; }
            h = (h + 1) & HMASK2;
        }
    }
}

// ---------------- K2: claimers of collided cells join the min + record claim idx ----------------
__global__ void k_phase2(const float* __restrict__ pts, const unsigned char* __restrict__ flag,
                         unsigned long long* __restrict__ slabB,
                         unsigned* __restrict__ claimB) {
    int g = blockIdx.x * blockDim.x + threadIdx.x;
    if (g >= NPTS) return;
    if (!flag[g]) return;                              // claimers only
    int b = g / NPB;
    int idx = g - b * NPB;
    const float* p = pts + (long long)g * 5;
    int cx, cy, cz;
    if (!point_cell(p, cx, cy, cz)) return;
    int lid = (cz * GY + cy) * GX + cx;
    unsigned h = (((unsigned)lid * 2654435761u) >> 17) & HMASK2;
    int base2 = b * HC2;
    while (true) {
        unsigned long long cur = slabB[base2 + (int)h];
        if (cur == EMPTY64) break;                     // cell not collided (typical)
        if ((unsigned)(cur >> 32) == (unsigned)lid) {  // collided: include self in min
            unsigned long long key = ((unsigned long long)(unsigned)lid << 32)
                                   | (unsigned long long)(unsigned)idx;
            atomicMin(&slabB[base2 + (int)h], key);
            claimB[base2 + (int)h] = (unsigned)idx;    // unique writer per cell
            break;
        }
        h = (h + 1) & HMASK2;
    }
}

// ---------------- K3: relocate stale flags (claim != min) ----------------
__global__ void k_fix(const unsigned long long* __restrict__ slabB,
                      const unsigned* __restrict__ claimB,
                      unsigned char* __restrict__ flag) {
    int s = blockIdx.x * blockDim.x + threadIdx.x;
    if (s >= NSLOT2) return;
    unsigned long long w = slabB[s];
    if (w == EMPTY64) return;
    int b = s >> 15;                                   // / HC2
    unsigned m = (unsigned)w;                          // true min idx
    unsigned c = claimB[s];                            // claimer idx (always written in phase2)
    if (c != m) {
        flag[b * NPB + (int)c] = 0;
        flag[b * NPB + (int)m] = 1;
    }
}

// ---------------- K4: leader flag + per-tile scan ----------------
__global__ void k_leader_scan(const unsigned char* __restrict__ flag,
                              int* __restrict__ rankT, int* __restrict__ tileSum) {
    int b = blockIdx.y;
    int tile = blockIdx.x;
    int idx = tile * 256 + threadIdx.x;
    int f = 0;
    if (idx < NPB) f = flag[b * NPB + idx] ? 1 : 0;
    __shared__ int sc[256];
    sc[threadIdx.x] = f;
    __syncthreads();
    for (int off = 1; off < 256; off <<= 1) {
        int v = sc[threadIdx.x];
        if ((int)threadIdx.x >= off) v += sc[threadIdx.x - off];
        __syncthreads();
        sc[threadIdx.x] = v;
        __syncthreads();
    }
    if (idx < NPB) rankT[b * NPB + idx] = sc[threadIdx.x] - f;  // exclusive in tile
    if (threadIdx.x == 255) tileSum[b * TILES_PAD + tile] = sc[255];
}

// ---------------- K5: per-batch scan of tile sums ----------------
__global__ void k_scan_tiles(const int* __restrict__ tileSum, int* __restrict__ tileOff) {
    int b = blockIdx.x;
    int t = threadIdx.x;
    __shared__ int sc[512];
    int v = (t < TILES) ? tileSum[b * TILES_PAD + t] : 0;
    sc[t] = v;
    __syncthreads();
    for (int off = 1; off < 512; off <<= 1) {
        int x = sc[t];
        if (t >= off) x += sc[t - off];
        __syncthreads();
        sc[t] = x;
        __syncthreads();
    }
    if (t < TILES) tileOff[b * TILES_PAD + t] = sc[t] - v;      // exclusive
}

// ---------------- K6: leaders write full row + coors + num(provisional); non-leaders -> mlist ----------------
__global__ void k_finish(const float* __restrict__ pts, const unsigned char* __restrict__ flag,
                         const unsigned long long* __restrict__ slabB,
                         const int* __restrict__ rankT, const int* __restrict__ tileOff,
                         float* __restrict__ out, int2* __restrict__ mlist,
                         unsigned* __restrict__ mcount) {
    int g = blockIdx.x * blockDim.x + threadIdx.x;
    if (g >= NPTS) return;
    int b = g / NPB;
    int idx = g - b * NPB;
    const float* p = pts + (long long)g * 5;
    int cx, cy, cz;
    if (!point_cell(p, cx, cy, cz)) return;
    if (flag[g]) {                                               // leader (== min idx == pos 0)
        int slot = tileOff[b * TILES_PAD + (idx >> 8)] + rankT[g];
        if (slot >= MAX_VOX) return;
        long long r = (long long)b * MAX_VOX + slot;
        float4* cr = (float4*)(out + OUT_COOR + r * 4);
        *cr = make_float4((float)b, (float)cz, (float)cy, (float)cx);
        out[OUT_NUM + r] = 1.f;                                  // multi cells corrected by k_multi
        float4* row = (float4*)(out + OUT_VOX + r * (MAX_PTS * 4));
        row[0] = make_float4(p[1], p[2], p[3], p[4]);
        float4 z4 = make_float4(0.f, 0.f, 0.f, 0.f);
        #pragma unroll
        for (int i = 1; i < MAX_PTS; i++) row[i] = z4;
    } else {
        // non-leader => collided cell; probe secondary for leader idx (rare ~4k)
        int lid = (cz * GY + cy) * GX + cx;
        unsigned h = (((unsigned)lid * 2654435761u) >> 17) & HMASK2;
        int base2 = b * HC2;
        unsigned minidx;
        while (true) {
            unsigned long long cur = slabB[base2 + (int)h];
            if ((unsigned)(cur >> 32) == (unsigned)lid) { minidx = (unsigned)cur; break; }
            h = (h + 1) & HMASK2;
        }
        int slot = tileOff[b * TILES_PAD + ((int)minidx >> 8)] + rankT[b * NPB + (int)minidx];
        if (slot >= MAX_VOX) return;
        unsigned m = atomicAdd(&mcount[b], 1u);
        if (m < MBCAP) mlist[(size_t)b * MBCAP + m] = make_int2(slot, idx);
    }
}

// ---------------- K7: rank + scatter multi-cell non-leaders; fix num ----------------
__global__ void k_multi(const float* __restrict__ pts,
                        const int2* __restrict__ mlist, const unsigned* __restrict__ mcount,
                        float* __restrict__ out) {
    int b = blockIdx.y;
    unsigned n = mcount[b];
    if (n > MBCAP) n = MBCAP;
    unsigned t = blockIdx.x * blockDim.x + threadIdx.x;
    const int2* lst = mlist + (size_t)b * MBCAP;
    bool active = (t < n);
    int2 e = active ? lst[t] : make_int2(-1, -1);   // (slot, idx)
    int pos = 1;                                    // leader (not in list) is pos 0
    int same = 0;                                   // same-slot entries incl. self
    __shared__ int2 sm[MTILE];
    for (unsigned chunk = 0; chunk < n; chunk += MTILE) {
        unsigned m = n - chunk;
        if (m > MTILE) m = MTILE;
        for (unsigned i = threadIdx.x; i < m; i += 256)
            sm[i] = lst[chunk + i];
        __syncthreads();
        if (active) {
            #pragma unroll 4
            for (unsigned j = 0; j < m; j++) {
                int2 o = sm[j];
                if (o.x == e.x) { same++; if (o.y < e.y) pos++; }
            }
        }
        __syncthreads();
    }
    if (!active) return;
    if (pos == 1) {                                 // smallest non-leader writes true count
        int cnt = same + 1;                         // + leader
        out[OUT_NUM + (long long)b * MAX_VOX + e.x] =
            (float)(cnt < MAX_PTS ? cnt : MAX_PTS);
    }
    if (pos >= MAX_PTS) return;
    const float* p = pts + ((long long)b * NPB + e.y) * 5;
    long long base = OUT_VOX + (((long long)b * MAX_VOX + e.x) * MAX_PTS + pos) * 4;
    float4* dst = (float4*)(out + base);
    *dst = make_float4(p[1], p[2], p[3], p[4]);
}

extern "C" void kernel_launch(void* const* d_in, const int* in_sizes, int n_in,
                              void* d_out, int out_size, void* d_ws, size_t ws_size,
                              hipStream_t stream) {
    const float* pts = (const float*)d_in[0];
    float* out = (float*)d_out;

    char* w = (char*)d_ws;
    unsigned* bm = (unsigned*)w;          w += (size_t)NB * WPB * 4;     // 11.26 MB
    unsigned long long* slabB = (unsigned long long*)w;
    w += (size_t)NSLOT2 * 8;                                             // 2 MB
    unsigned* claimB = (unsigned*)w;      w += (size_t)NSLOT2 * 4;       // 1 MB
    unsigned char* flag = (unsigned char*)w; w += (size_t)NPTS;          // 0.96 MB
    int* rankT = (int*)w;    w += (size_t)NPTS * 4;                      // 3.84 MB
    int* tileSum = (int*)w;  w += (size_t)NB * TILES_PAD * 4;
    int* tileOff = (int*)w;  w += (size_t)NB * TILES_PAD * 4;
    int2* mlist = (int2*)w;  w += (size_t)NB * MBCAP * 8;                // 0.5 MB
    unsigned* mcount = (unsigned*)w; w += 256;

    k_init<<<dim3(4096), dim3(256), 0, stream>>>(out, (uint4*)bm, (ulonglong2*)slabB,
                                                 (uint4*)flag, mcount);
    k_phase1<<<dim3((NPTS + 255) / 256), dim3(256), 0, stream>>>(pts, bm, slabB, flag);
    k_phase2<<<dim3((NPTS + 255) / 256), dim3(256), 0, stream>>>(pts, flag, slabB, claimB);
    k_fix<<<dim3(NSLOT2 / 256), dim3(256), 0, stream>>>(slabB, claimB, flag);
    k_leader_scan<<<dim3(TILES, NB), dim3(256), 0, stream>>>(flag, rankT, tileSum);
    k_scan_tiles<<<dim3(NB), dim3(512), 0, stream>>>(tileSum, tileOff);
    k_finish<<<dim3((NPTS + 255) / 256), dim3(256), 0, stream>>>(pts, flag, slabB,
                                                                 rankT, tileOff, out, mlist, mcount);
    k_multi<<<dim3(MBCAP / 256, NB), dim3(256), 0, stream>>>(pts, mlist, mcount, out);
}